// Round 3
// baseline (453.771 us; speedup 1.0000x reference)
//
#include <hip/hip_runtime.h>
#include <hip/hip_bf16.h>
#include <hip/hip_cooperative_groups.h>

namespace cg = cooperative_groups;

#define HDIM 128

typedef __attribute__((ext_vector_type(8))) short short8;
typedef __attribute__((ext_vector_type(4))) float floatx4;

__device__ __forceinline__ float bf2f(unsigned short u) {
    return __uint_as_float(((unsigned)u) << 16);
}
__device__ __forceinline__ unsigned short f2b(float f) {
    __hip_bfloat16 h = __float2bfloat16(f);
    return __builtin_bit_cast(unsigned short, h);
}
__device__ __forceinline__ float ldv(const void* p, size_t i, int flag) {
    return flag ? bf2f(((const unsigned short*)p)[i]) : ((const float*)p)[i];
}
__device__ __forceinline__ short8 pack8(float4 a, float4 b) {
    short8 r;
    r[0] = (short)f2b(a.x); r[1] = (short)f2b(a.y);
    r[2] = (short)f2b(a.z); r[3] = (short)f2b(a.w);
    r[4] = (short)f2b(b.x); r[5] = (short)f2b(b.y);
    r[6] = (short)f2b(b.z); r[7] = (short)f2b(b.w);
    return r;
}

// ---------------------------------------------------------------------------
// Block-local dtype detect (same result in every block). flag=1 -> bf16,
// 0 -> f32. Uses caller-provided 256-int scratch (LDS).
// ---------------------------------------------------------------------------
__device__ __forceinline__ int local_detect_s(const unsigned short* zbits, int* red) {
    int tid = threadIdx.x;
    int cnt = 0;
    for (int i = tid; i < 4096; i += 256) {
        int ex = (zbits[i] >> 7) & 0xFF;
        if (ex >= 100 && ex <= 140) cnt++;
    }
    red[tid] = cnt;
    __syncthreads();
    for (int s = 128; s > 0; s >>= 1) {
        if (tid < s) red[tid] += red[tid + s];
        __syncthreads();
    }
    int f = (red[0] >= 3686) ? 1 : 0;
    __syncthreads();
    return f;
}

// ===========================================================================
// FUSED cooperative kernel: phase A (prep) | grid.sync | phase B (proj)
// | grid.sync | phase C (edge).  One dispatch instead of three: removes two
// kernel-boundary flush/launch costs, keeps clocks ramped, keeps L2 warm.
// Every block computes the dtype flag locally (no global flag dependency).
// ===========================================================================
__global__ __launch_bounds__(256) void fused_kernel(
    const void* __restrict__ Zg, const void* __restrict__ Zd,
    const int* __restrict__ edges_gd, const int* __restrict__ edges_gg,
    const void* __restrict__ w1_gd, const void* __restrict__ b1_gd,
    const void* __restrict__ w2_gd, const void* __restrict__ b2_gd,
    const void* __restrict__ w1_gg, const void* __restrict__ b1_gg,
    const void* __restrict__ w2_gg, const void* __restrict__ b2_gg,
    unsigned short* __restrict__ img, float* __restrict__ params,
    unsigned short* __restrict__ A_gd, unsigned short* __restrict__ B_gd,
    unsigned short* __restrict__ A_gg, unsigned short* __restrict__ B_gg,
    void* __restrict__ out,
    int NG, int ND, int E, int gblk, int dblk, int nb)
{
    cg::grid_group grid = cg::this_grid();
    __shared__ uint4 sW[2048];      // 32 KB: detect scratch / W tile / out staging

    int tid  = threadIdx.x;
    int lane = tid & 63;
    int wave = tid >> 6;
    int flag = local_detect_s((const unsigned short*)Zg, (int*)sW);
    int b = blockIdx.x;

    // ---- phase A: build swizzled W images (256 blocks, 1 value/thread) + params
    if (b < 256) {
        int im  = b >> 6;           // image id, 64 blocks each
        int sub = b & 63;           // 2 k-rows per block
        const void* w1 = (im < 2) ? w1_gd : w1_gg;
        int part = im & 1;
        unsigned short* o = img + im * 16384;
        int n = tid & 127;
        int k = sub * 2 + (tid >> 7);
        unsigned short v = flag
            ? ((const unsigned short*)w1)[(size_t)(part * 128 + k) * 128 + n]
            : f2b(((const float*)w1)[(size_t)(part * 128 + k) * 128 + n]);
        o[n * 128 + (((k >> 3) ^ (n & 15)) << 3) + (k & 7)] = v;
        if (b == 0) {
            if (tid < 128) {
                params[tid]       = ldv(b1_gd, tid, flag);
                params[256 + tid] = ldv(b1_gg, tid, flag);
            } else {
                params[tid]       = ldv(w2_gd, tid - 128, flag);
                params[256 + tid] = ldv(w2_gg, tid - 128, flag);
            }
            if (tid == 0) {
                params[512] = ldv(b2_gd, 0, flag);
                params[513] = ldv(b2_gg, 0, flag);
            }
        }
    }
    __threadfence();
    grid.sync();
    __threadfence();

    // ---- phase B: projection instances (grid-stride) ----------------------
    {
        int nl   = lane & 15;
        int quad = lane >> 4;
        const uint4* Wimg = (const uint4*)img;
        int ninst = 3 * gblk + dblk;
        for (int inst = b; inst < ninst; inst += gridDim.x) {
            int ph = (inst >= gblk) + (inst >= 2 * gblk) + (inst >= 3 * gblk);
            bool gene = ph < 3;
            int blk = inst - ph * gblk;
            int M = gene ? NG : ND;
            const void* Z = gene ? Zg : Zd;
            const uint4* im = Wimg + (ph == 0 ? 0 : ph == 1 ? 2 : ph == 2 ? 3 : 1) * 2048;
            unsigned short* Out = ph == 0 ? A_gd : ph == 1 ? A_gg : ph == 2 ? B_gg : B_gd;
            const float* bias = ph == 0 ? params : ph == 1 ? params + 256 : nullptr;

            __syncthreads();   // prev iteration's staging reads done
#pragma unroll
            for (int i = 0; i < 8; ++i) sW[tid + i * 256] = im[tid + i * 256];

            int row0 = blk * 128 + wave * 32 + nl;
            int row1 = row0 + 16;
            int r0c = row0 < M ? row0 : (M - 1);
            int r1c = row1 < M ? row1 : (M - 1);

            short8 zf[2][4];
            if (flag) {
                const uint4* z0 = (const uint4*)Z + (size_t)r0c * 16;
                const uint4* z1 = (const uint4*)Z + (size_t)r1c * 16;
#pragma unroll
                for (int kc = 0; kc < 4; ++kc) {
                    zf[0][kc] = __builtin_bit_cast(short8, z0[kc * 4 + quad]);
                    zf[1][kc] = __builtin_bit_cast(short8, z1[kc * 4 + quad]);
                }
            } else {
                const float4* z0 = (const float4*)Z + (size_t)r0c * 32;
                const float4* z1 = (const float4*)Z + (size_t)r1c * 32;
#pragma unroll
                for (int kc = 0; kc < 4; ++kc) {
                    int o = kc * 8 + quad * 2;
                    zf[0][kc] = pack8(z0[o], z0[o + 1]);
                    zf[1][kc] = pack8(z1[o], z1[o + 1]);
                }
            }

            __syncthreads();

            floatx4 acc[2][8];
#pragma unroll
            for (int rt = 0; rt < 2; ++rt)
#pragma unroll
                for (int nt = 0; nt < 8; ++nt)
                    acc[rt][nt] = (floatx4){0.f, 0.f, 0.f, 0.f};

#pragma unroll
            for (int kc = 0; kc < 4; ++kc) {
                int p = (kc * 4 + quad) ^ nl;   // undo XOR swizzle
#pragma unroll
                for (int nt = 0; nt < 8; ++nt) {
                    short8 wf = __builtin_bit_cast(short8, sW[(nt * 16 + nl) * 16 + p]);
                    acc[0][nt] = __builtin_amdgcn_mfma_f32_16x16x32_bf16(wf, zf[0][kc], acc[0][nt], 0, 0, 0);
                    acc[1][nt] = __builtin_amdgcn_mfma_f32_16x16x32_bf16(wf, zf[1][kc], acc[1][nt], 0, 0, 0);
                }
            }

            // LDS-staged coalesced epilogue (264B padded stride)
            char* sOb = (char*)sW;
            __syncthreads();   // all waves done reading W
#pragma unroll
            for (int rt = 0; rt < 2; ++rt) {
                int h = wave * 16 + nl;
#pragma unroll
                for (int nt = 0; nt < 8; ++nt) {
                    float4 bv = {0.f, 0.f, 0.f, 0.f};
                    if (bias) bv = *(const float4*)(bias + nt * 16 + quad * 4);
                    unsigned lo = ((unsigned)f2b(acc[rt][nt][0] + bv.x)) |
                                  (((unsigned)f2b(acc[rt][nt][1] + bv.y)) << 16);
                    unsigned hi = ((unsigned)f2b(acc[rt][nt][2] + bv.z)) |
                                  (((unsigned)f2b(acc[rt][nt][3] + bv.w)) << 16);
                    uint2 v; v.x = lo; v.y = hi;
                    *(uint2*)(sOb + h * 264 + nt * 32 + quad * 8) = v;
                }
                __syncthreads();
#pragma unroll
                for (int j = 0; j < 4; ++j) {
                    int r = blk * 128 + rt * 16 + j * 32 + (tid >> 4);
                    uint4 v = *(const uint4*)(sOb + (j * 16 + (tid >> 4)) * 264 + (tid & 15) * 16);
                    if (r < M)
                        *(uint4*)(Out + (size_t)r * HDIM + (tid & 15) * 8) = v;
                }
                if (rt == 0) __syncthreads();
            }
        }
    }
    __threadfence();
    grid.sync();
    __threadfence();

    // ---- phase C: edge chunks (grid-stride, 64 edges per chunk) -----------
    {
        int nl  = lane & 7;    // lane within edge-group
        int grp = lane >> 3;   // 8 groups per wave
        int nchunk = 2 * nb;
        for (int c = b; c < nchunk; c += gridDim.x) {
            int rel = (c >= nb) ? 1 : 0;
            int blk = c - rel * nb;
            const int* edges = rel ? edges_gg : edges_gd;
            const unsigned short* A = rel ? A_gg : A_gd;
            const unsigned short* B = rel ? B_gg : B_gd;
            const float* w2 = params + 128 + rel * 256;
            float b2 = params[512 + rel];

            float w2f[16];
#pragma unroll
            for (int i = 0; i < 4; ++i) {
                float4 t = *(const float4*)(w2 + nl * 16 + i * 4);
                w2f[i * 4 + 0] = t.x; w2f[i * 4 + 1] = t.y;
                w2f[i * 4 + 2] = t.z; w2f[i * 4 + 3] = t.w;
            }

            int e0 = blk * 64 + (wave * 8 + grp) * 2;
            int e1 = e0 + 1;
            int emax = E - 2 > 0 ? E - 2 : 0;
            int ec = e0 < emax ? e0 : emax;
            int sel = e0 - ec;
            int2 sp = *(const int2*)(edges + ec);
            int2 dp = *(const int2*)(edges + E + ec);
            int src0 = sel ? sp.y : sp.x;
            int dst0 = sel ? dp.y : dp.x;
            int src1 = sp.y;
            int dst1 = dp.y;

            const uint4* a0p = (const uint4*)(A + (size_t)src0 * HDIM) + nl * 2;
            const uint4* b0p = (const uint4*)(B + (size_t)dst0 * HDIM) + nl * 2;
            const uint4* a1p = (const uint4*)(A + (size_t)src1 * HDIM) + nl * 2;
            const uint4* b1p = (const uint4*)(B + (size_t)dst1 * HDIM) + nl * 2;
            uint4 a0[2] = {a0p[0], a0p[1]};
            uint4 c0[2] = {b0p[0], b0p[1]};
            uint4 a1[2] = {a1p[0], a1p[1]};
            uint4 c1[2] = {b1p[0], b1p[1]};

            float acc0 = 0.f, acc1 = 0.f;
#pragma unroll
            for (int i = 0; i < 2; ++i) {
                const unsigned* au0 = (const unsigned*)&a0[i];
                const unsigned* cu0 = (const unsigned*)&c0[i];
                const unsigned* au1 = (const unsigned*)&a1[i];
                const unsigned* cu1 = (const unsigned*)&c1[i];
#pragma unroll
                for (int j = 0; j < 4; ++j) {
                    int ch = i * 8 + j * 2;
                    float x0 = __uint_as_float(au0[j] << 16);
                    float x1 = __uint_as_float(au0[j] & 0xffff0000u);
                    float y0 = __uint_as_float(cu0[j] << 16);
                    float y1 = __uint_as_float(cu0[j] & 0xffff0000u);
                    acc0 = fmaf(fmaxf(x0 + y0, 0.f), w2f[ch], acc0);
                    acc0 = fmaf(fmaxf(x1 + y1, 0.f), w2f[ch + 1], acc0);
                    float u0 = __uint_as_float(au1[j] << 16);
                    float u1 = __uint_as_float(au1[j] & 0xffff0000u);
                    float v0 = __uint_as_float(cu1[j] << 16);
                    float v1 = __uint_as_float(cu1[j] & 0xffff0000u);
                    acc1 = fmaf(fmaxf(u0 + v0, 0.f), w2f[ch], acc1);
                    acc1 = fmaf(fmaxf(u1 + v1, 0.f), w2f[ch + 1], acc1);
                }
            }
            acc0 += __shfl_xor(acc0, 1); acc1 += __shfl_xor(acc1, 1);
            acc0 += __shfl_xor(acc0, 2); acc1 += __shfl_xor(acc1, 2);
            acc0 += __shfl_xor(acc0, 4); acc1 += __shfl_xor(acc1, 4);

            if (nl == 0) {
                size_t base = (size_t)rel * E;
                if (e0 < E) {
                    float r = acc0 + b2;
                    if (flag) ((unsigned short*)out)[base + e0] = f2b(r);
                    else      ((float*)out)[base + e0] = r;
                }
                if (e1 < E) {
                    float r = acc1 + b2;
                    if (flag) ((unsigned short*)out)[base + e1] = f2b(r);
                    else      ((float*)out)[base + e1] = r;
                }
            }
        }
    }
}

// ===========================================================================
// Fallback path kernels (3-dispatch pipeline, verified r0/r2 versions)
// ===========================================================================
__device__ __forceinline__ int local_detect(const unsigned short* zbits) {
    __shared__ int red[256];
    return local_detect_s(zbits, red);
}

__global__ __launch_bounds__(256) void prep_kernel(
    const unsigned short* __restrict__ zbits,
    const void* __restrict__ w1_gd, const void* __restrict__ w1_gg,
    const void* __restrict__ b1_gd, const void* __restrict__ w2_gd,
    const void* __restrict__ b2_gd, const void* __restrict__ b1_gg,
    const void* __restrict__ w2_gg, const void* __restrict__ b2_gg,
    unsigned short* __restrict__ img, float* __restrict__ params,
    int* __restrict__ flagout)
{
    int flag = local_detect(zbits);
    int b = blockIdx.x;
    int tid = threadIdx.x;
    if (b < 32) {
        int im   = b >> 3;
        int sub  = b & 7;
        const void* w1 = (im < 2) ? w1_gd : w1_gg;
        int part = im & 1;
        unsigned short* out = img + im * 16384;
        int n = tid & 127;
#pragma unroll
        for (int it = 0; it < 8; ++it) {
            int k = sub * 16 + it * 2 + (tid >> 7);
            unsigned short v = flag
                ? ((const unsigned short*)w1)[(size_t)(part * 128 + k) * 128 + n]
                : f2b(((const float*)w1)[(size_t)(part * 128 + k) * 128 + n]);
            out[n * 128 + (((k >> 3) ^ (n & 15)) << 3) + (k & 7)] = v;
        }
    } else {
        if (tid < 128) {
            params[tid]       = ldv(b1_gd, tid, flag);
            params[256 + tid] = ldv(b1_gg, tid, flag);
        } else {
            params[tid]       = ldv(w2_gd, tid - 128, flag);
            params[256 + tid] = ldv(w2_gg, tid - 128, flag);
        }
        if (tid == 0) {
            params[512] = ldv(b2_gd, 0, flag);
            params[513] = ldv(b2_gg, 0, flag);
            *flagout = flag;
        }
    }
}

__global__ __launch_bounds__(256) void proj_all_kernel(
    const void* __restrict__ Zg, const void* __restrict__ Zd,
    const uint4* __restrict__ Wimg, const float* __restrict__ params,
    unsigned short* __restrict__ A_gd, unsigned short* __restrict__ B_gd,
    unsigned short* __restrict__ A_gg, unsigned short* __restrict__ B_gg,
    int NG, int ND, int gblk, const int* __restrict__ flagp)
{
    __shared__ uint4 sW[2048];
    int tid  = threadIdx.x;
    int lane = tid & 63;
    int wave = tid >> 6;
    int nl   = lane & 15;
    int quad = lane >> 4;
    int flag = *flagp;

    int b  = blockIdx.x;
    int ph = (b >= gblk) + (b >= 2 * gblk) + (b >= 3 * gblk);
    bool gene = ph < 3;
    int blk = b - ph * gblk;
    int M = gene ? NG : ND;
    const void* Z = gene ? Zg : Zd;
    const uint4* im = Wimg + (ph == 0 ? 0 : ph == 1 ? 2 : ph == 2 ? 3 : 1) * 2048;
    unsigned short* Out = ph == 0 ? A_gd : ph == 1 ? A_gg : ph == 2 ? B_gg : B_gd;
    const float* bias = ph == 0 ? params : ph == 1 ? params + 256 : nullptr;

#pragma unroll
    for (int i = 0; i < 8; ++i) sW[tid + i * 256] = im[tid + i * 256];

    int row0 = blk * 128 + wave * 32 + nl;
    int row1 = row0 + 16;
    int r0c = row0 < M ? row0 : (M - 1);
    int r1c = row1 < M ? row1 : (M - 1);

    short8 zf[2][4];
    if (flag) {
        const uint4* z0 = (const uint4*)Z + (size_t)r0c * 16;
        const uint4* z1 = (const uint4*)Z + (size_t)r1c * 16;
#pragma unroll
        for (int kc = 0; kc < 4; ++kc) {
            zf[0][kc] = __builtin_bit_cast(short8, z0[kc * 4 + quad]);
            zf[1][kc] = __builtin_bit_cast(short8, z1[kc * 4 + quad]);
        }
    } else {
        const float4* z0 = (const float4*)Z + (size_t)r0c * 32;
        const float4* z1 = (const float4*)Z + (size_t)r1c * 32;
#pragma unroll
        for (int kc = 0; kc < 4; ++kc) {
            int o = kc * 8 + quad * 2;
            zf[0][kc] = pack8(z0[o], z0[o + 1]);
            zf[1][kc] = pack8(z1[o], z1[o + 1]);
        }
    }

    __syncthreads();

    floatx4 acc[2][8];
#pragma unroll
    for (int rt = 0; rt < 2; ++rt)
#pragma unroll
        for (int nt = 0; nt < 8; ++nt)
            acc[rt][nt] = (floatx4){0.f, 0.f, 0.f, 0.f};

#pragma unroll
    for (int kc = 0; kc < 4; ++kc) {
        int p = (kc * 4 + quad) ^ nl;
#pragma unroll
        for (int nt = 0; nt < 8; ++nt) {
            short8 wf = __builtin_bit_cast(short8, sW[(nt * 16 + nl) * 16 + p]);
            acc[0][nt] = __builtin_amdgcn_mfma_f32_16x16x32_bf16(wf, zf[0][kc], acc[0][nt], 0, 0, 0);
            acc[1][nt] = __builtin_amdgcn_mfma_f32_16x16x32_bf16(wf, zf[1][kc], acc[1][nt], 0, 0, 0);
        }
    }

    char* sOb = (char*)sW;
    __syncthreads();
#pragma unroll
    for (int rt = 0; rt < 2; ++rt) {
        int h = wave * 16 + nl;
#pragma unroll
        for (int nt = 0; nt < 8; ++nt) {
            float4 bv = {0.f, 0.f, 0.f, 0.f};
            if (bias) bv = *(const float4*)(bias + nt * 16 + quad * 4);
            unsigned lo = ((unsigned)f2b(acc[rt][nt][0] + bv.x)) |
                          (((unsigned)f2b(acc[rt][nt][1] + bv.y)) << 16);
            unsigned hi = ((unsigned)f2b(acc[rt][nt][2] + bv.z)) |
                          (((unsigned)f2b(acc[rt][nt][3] + bv.w)) << 16);
            uint2 v; v.x = lo; v.y = hi;
            *(uint2*)(sOb + h * 264 + nt * 32 + quad * 8) = v;
        }
        __syncthreads();
#pragma unroll
        for (int j = 0; j < 4; ++j) {
            int r = blk * 128 + rt * 16 + j * 32 + (tid >> 4);
            uint4 v = *(const uint4*)(sOb + (j * 16 + (tid >> 4)) * 264 + (tid & 15) * 16);
            if (r < M)
                *(uint4*)(Out + (size_t)r * HDIM + (tid & 15) * 8) = v;
        }
        if (rt == 0) __syncthreads();
    }
}

__global__ __launch_bounds__(256) void edge_kernel(
    const int* __restrict__ edges_gd, const int* __restrict__ edges_gg,
    const unsigned short* __restrict__ A_gd, const unsigned short* __restrict__ B_gd,
    const unsigned short* __restrict__ A_gg, const unsigned short* __restrict__ B_gg,
    const float* __restrict__ params,
    void* __restrict__ out, int E, int nb, const int* __restrict__ flagp)
{
    int rel = ((int)blockIdx.x >= nb) ? 1 : 0;
    int blk = blockIdx.x - rel * nb;
    const int* edges = rel ? edges_gg : edges_gd;
    const unsigned short* A = rel ? A_gg : A_gd;
    const unsigned short* B = rel ? B_gg : B_gd;
    const float* w2 = params + 128 + rel * 256;
    float b2 = params[512 + rel];

    int tid  = threadIdx.x;
    int lane = tid & 63;
    int wave = tid >> 6;
    int nl   = lane & 7;
    int grp  = lane >> 3;

    float w2f[16];
#pragma unroll
    for (int i = 0; i < 4; ++i) {
        float4 t = *(const float4*)(w2 + nl * 16 + i * 4);
        w2f[i * 4 + 0] = t.x; w2f[i * 4 + 1] = t.y;
        w2f[i * 4 + 2] = t.z; w2f[i * 4 + 3] = t.w;
    }

    int e0 = blk * 64 + (wave * 8 + grp) * 2;
    int e1 = e0 + 1;
    int emax = E - 2 > 0 ? E - 2 : 0;
    int ec = e0 < emax ? e0 : emax;
    int sel = e0 - ec;
    int2 sp = *(const int2*)(edges + ec);
    int2 dp = *(const int2*)(edges + E + ec);
    int src0 = sel ? sp.y : sp.x;
    int dst0 = sel ? dp.y : dp.x;
    int src1 = sp.y;
    int dst1 = dp.y;

    const uint4* a0p = (const uint4*)(A + (size_t)src0 * HDIM) + nl * 2;
    const uint4* b0p = (const uint4*)(B + (size_t)dst0 * HDIM) + nl * 2;
    const uint4* a1p = (const uint4*)(A + (size_t)src1 * HDIM) + nl * 2;
    const uint4* b1p = (const uint4*)(B + (size_t)dst1 * HDIM) + nl * 2;
    uint4 a0[2] = {a0p[0], a0p[1]};
    uint4 c0[2] = {b0p[0], b0p[1]};
    uint4 a1[2] = {a1p[0], a1p[1]};
    uint4 c1[2] = {b1p[0], b1p[1]};

    float acc0 = 0.f, acc1 = 0.f;
#pragma unroll
    for (int i = 0; i < 2; ++i) {
        const unsigned* au0 = (const unsigned*)&a0[i];
        const unsigned* cu0 = (const unsigned*)&c0[i];
        const unsigned* au1 = (const unsigned*)&a1[i];
        const unsigned* cu1 = (const unsigned*)&c1[i];
#pragma unroll
        for (int j = 0; j < 4; ++j) {
            int ch = i * 8 + j * 2;
            float x0 = __uint_as_float(au0[j] << 16);
            float x1 = __uint_as_float(au0[j] & 0xffff0000u);
            float y0 = __uint_as_float(cu0[j] << 16);
            float y1 = __uint_as_float(cu0[j] & 0xffff0000u);
            acc0 = fmaf(fmaxf(x0 + y0, 0.f), w2f[ch], acc0);
            acc0 = fmaf(fmaxf(x1 + y1, 0.f), w2f[ch + 1], acc0);
            float u0 = __uint_as_float(au1[j] << 16);
            float u1 = __uint_as_float(au1[j] & 0xffff0000u);
            float v0 = __uint_as_float(cu1[j] << 16);
            float v1 = __uint_as_float(cu1[j] & 0xffff0000u);
            acc1 = fmaf(fmaxf(u0 + v0, 0.f), w2f[ch], acc1);
            acc1 = fmaf(fmaxf(u1 + v1, 0.f), w2f[ch + 1], acc1);
        }
    }
    acc0 += __shfl_xor(acc0, 1); acc1 += __shfl_xor(acc1, 1);
    acc0 += __shfl_xor(acc0, 2); acc1 += __shfl_xor(acc1, 2);
    acc0 += __shfl_xor(acc0, 4); acc1 += __shfl_xor(acc1, 4);

    if (nl == 0) {
        int flag = *flagp;
        size_t base = (size_t)rel * E;
        if (e0 < E) {
            float r = acc0 + b2;
            if (flag) ((unsigned short*)out)[base + e0] = f2b(r);
            else      ((float*)out)[base + e0] = r;
        }
        if (e1 < E) {
            float r = acc1 + b2;
            if (flag) ((unsigned short*)out)[base + e1] = f2b(r);
            else      ((float*)out)[base + e1] = r;
        }
    }
}

__global__ __launch_bounds__(256) void detect_kernel(
    const unsigned short* __restrict__ zbits, int* __restrict__ flag)
{
    int f = local_detect(zbits);
    if (threadIdx.x == 0) *flag = f;
}

__global__ __launch_bounds__(128) void naive_edge_kernel(
    const int* __restrict__ edges,
    const void* __restrict__ zsrc, const void* __restrict__ zdst,
    const void* __restrict__ w1, const void* __restrict__ b1,
    const void* __restrict__ w2, const void* __restrict__ b2,
    void* __restrict__ out, size_t eoff, int E,
    const int* __restrict__ flagp)
{
    int flag = flagp ? *flagp : 0;
    __shared__ float zs[128], zd[128], red[128];
    int e = blockIdx.x;
    int n = threadIdx.x;
    int src = edges[e], dst = edges[E + e];
    zs[n] = ldv(zsrc, (size_t)src * HDIM + n, flag);
    zd[n] = ldv(zdst, (size_t)dst * HDIM + n, flag);
    __syncthreads();
    float acc = ldv(b1, n, flag);
    for (int k = 0; k < 128; ++k) acc = fmaf(zs[k], ldv(w1, (size_t)k * HDIM + n, flag), acc);
    for (int k = 0; k < 128; ++k) acc = fmaf(zd[k], ldv(w1, (size_t)(128 + k) * HDIM + n, flag), acc);
    red[n] = fmaxf(acc, 0.f) * ldv(w2, n, flag);
    __syncthreads();
    for (int s = 64; s > 0; s >>= 1) {
        if (n < s) red[n] += red[n + s];
        __syncthreads();
    }
    if (n == 0) {
        float r = red[0] + ldv(b2, 0, flag);
        if (flag) ((unsigned short*)out)[eoff + e] = f2b(r);
        else      ((float*)out)[eoff + e] = r;
    }
}

extern "C" void kernel_launch(void* const* d_in, const int* in_sizes, int n_in,
                              void* d_out, int out_size, void* d_ws, size_t ws_size,
                              hipStream_t stream)
{
    const void* z_gene = d_in[0];
    const void* z_dis  = d_in[1];
    const int* edges_gd = (const int*)d_in[2];
    const int* edges_gg = (const int*)d_in[3];
    const void* w1_gd = d_in[4];
    const void* b1_gd = d_in[5];
    const void* w2_gd = d_in[6];
    const void* b2_gd = d_in[7];
    const void* w1_gg = d_in[8];
    const void* b1_gg = d_in[9];
    const void* w2_gg = d_in[10];
    const void* b2_gg = d_in[11];

    int NG = in_sizes[0] / HDIM;   // 100000
    int ND = in_sizes[1] / HDIM;   // 20000
    int E  = in_sizes[2] / 2;      // 500000

    // workspace layout (bytes)
    size_t off_flag   = 0;
    size_t off_params = 256;
    size_t off_img    = 2560;
    size_t off_Agd    = off_img + 131072;
    size_t off_Bgd    = off_Agd + (size_t)NG * HDIM * 2;
    size_t off_Agg    = off_Bgd + (size_t)ND * HDIM * 2;
    size_t off_Bgg    = off_Agg + (size_t)NG * HDIM * 2;
    size_t need       = off_Bgg + (size_t)NG * HDIM * 2;

    char* ws = (char*)d_ws;

    if (ws_size < need) {
        const int* flagp = nullptr;
        if (ws_size >= 16) {
            detect_kernel<<<1, 256, 0, stream>>>((const unsigned short*)z_gene, (int*)ws);
            flagp = (const int*)ws;
        }
        naive_edge_kernel<<<E, 128, 0, stream>>>(edges_gd, z_gene, z_dis,
                                                 w1_gd, b1_gd, w2_gd, b2_gd,
                                                 d_out, 0, E, flagp);
        naive_edge_kernel<<<E, 128, 0, stream>>>(edges_gg, z_gene, z_gene,
                                                 w1_gg, b1_gg, w2_gg, b2_gg,
                                                 d_out, (size_t)E, E, flagp);
        return;
    }

    int* flag = (int*)(ws + off_flag);
    float* params = (float*)(ws + off_params);
    unsigned short* img = (unsigned short*)(ws + off_img);
    unsigned short* Agd = (unsigned short*)(ws + off_Agd);
    unsigned short* Bgd = (unsigned short*)(ws + off_Bgd);
    unsigned short* Agg = (unsigned short*)(ws + off_Agg);
    unsigned short* Bgg = (unsigned short*)(ws + off_Bgg);

    int gblk = (NG + 127) / 128;
    int dblk = (ND + 127) / 128;
    int nb   = (E + 63) / 64;

    // ---- cooperative fused path (one dispatch) ----------------------------
    static int s_grid = -1;   // occupancy-sized grid, computed once
    if (s_grid < 0) {
        int per_cu = 0;
        hipError_t e1 = hipOccupancyMaxActiveBlocksPerMultiprocessor(
            &per_cu, (const void*)fused_kernel, 256, 0);
        hipDeviceProp_t props;
        int dev = 0;
        hipGetDevice(&dev);
        hipError_t e2 = hipGetDeviceProperties(&props, dev);
        if (e1 == hipSuccess && e2 == hipSuccess && per_cu > 0) {
            long g = (long)per_cu * props.multiProcessorCount;
            if (g > 2048) g = 2048;
            s_grid = (int)g;
        } else {
            s_grid = 0;
        }
    }

    bool coop_done = false;
    if (s_grid >= 256) {
        void* outp = d_out;
        void* args[] = {
            (void*)&z_gene, (void*)&z_dis, (void*)&edges_gd, (void*)&edges_gg,
            (void*)&w1_gd, (void*)&b1_gd, (void*)&w2_gd, (void*)&b2_gd,
            (void*)&w1_gg, (void*)&b1_gg, (void*)&w2_gg, (void*)&b2_gg,
            (void*)&img, (void*)&params,
            (void*)&Agd, (void*)&Bgd, (void*)&Agg, (void*)&Bgg,
            (void*)&outp, (void*)&NG, (void*)&ND, (void*)&E,
            (void*)&gblk, (void*)&dblk, (void*)&nb
        };
        hipError_t e = hipLaunchCooperativeKernel(
            (const void*)fused_kernel, dim3(s_grid), dim3(256), args, 0, stream);
        coop_done = (e == hipSuccess);
        if (!coop_done) s_grid = 0;   // don't retry every capture
    }
    if (coop_done) return;

    // ---- fallback: verified 3-dispatch pipeline ---------------------------
    prep_kernel<<<33, 256, 0, stream>>>((const unsigned short*)z_gene,
                                        w1_gd, w1_gg, b1_gd, w2_gd, b2_gd,
                                        b1_gg, w2_gg, b2_gg, img, params, flag);

    const uint4* img4 = (const uint4*)img;
    proj_all_kernel<<<3 * gblk + dblk, 256, 0, stream>>>(z_gene, z_dis, img4, params,
                                                         Agd, Bgd, Agg, Bgg,
                                                         NG, ND, gblk, flag);

    edge_kernel<<<2 * nb, 256, 0, stream>>>(edges_gd, edges_gg, Agd, Bgd, Agg, Bgg,
                                            params, d_out, E, nb, flag);
}

// Round 4
// 240.476 us; speedup vs baseline: 1.8870x; 1.8870x over previous
//
#include <hip/hip_runtime.h>
#include <hip/hip_bf16.h>

#define HDIM 128

typedef __attribute__((ext_vector_type(8))) short short8;
typedef __attribute__((ext_vector_type(4))) float floatx4;

__device__ __forceinline__ float bf2f(unsigned short u) {
    return __uint_as_float(((unsigned)u) << 16);
}
__device__ __forceinline__ unsigned short f2b(float f) {
    __hip_bfloat16 h = __float2bfloat16(f);
    return __builtin_bit_cast(unsigned short, h);
}
__device__ __forceinline__ float ldv(const void* p, size_t i, int flag) {
    return flag ? bf2f(((const unsigned short*)p)[i]) : ((const float*)p)[i];
}
__device__ __forceinline__ short8 pack8(float4 a, float4 b) {
    short8 r;
    r[0] = (short)f2b(a.x); r[1] = (short)f2b(a.y);
    r[2] = (short)f2b(a.z); r[3] = (short)f2b(a.w);
    r[4] = (short)f2b(b.x); r[5] = (short)f2b(b.y);
    r[6] = (short)f2b(b.z); r[7] = (short)f2b(b.w);
    return r;
}

// ---------------------------------------------------------------------------
// Block-local dtype detect (same result in every block). flag=1 -> bf16,
// 0 -> f32. Uses caller-provided 256-int scratch (LDS).
// ---------------------------------------------------------------------------
__device__ __forceinline__ int local_detect_s(const unsigned short* zbits, int* red) {
    int tid = threadIdx.x;
    int cnt = 0;
    for (int i = tid; i < 4096; i += 256) {
        int ex = (zbits[i] >> 7) & 0xFF;
        if (ex >= 100 && ex <= 140) cnt++;
    }
    red[tid] = cnt;
    __syncthreads();
    for (int s = 128; s > 0; s >>= 1) {
        if (tid < s) red[tid] += red[tid + s];
        __syncthreads();
    }
    int f = (red[0] >= 3686) ? 1 : 0;
    __syncthreads();
    return f;
}

// ---------------------------------------------------------------------------
// proj_all v3: self-contained (prep dispatch eliminated -> 2 total dispatches,
// each kernel boundary measured ~20us: r2 3-dispatch overhead 91us vs r3
// 1-dispatch overhead 47us).
// ONE (phase, rowblock) per block.  Grid = 3*gblk + dblk.
// ph0: z_gene x W(gd,top) -> A_gd (+b1_gd)   ph1: z_gene x W(gg,top) -> A_gg (+b1_gg)
// ph2: z_gene x W(gg,bot) -> B_gg            ph3: z_dis  x W(gd,bot) -> B_gd
// Each block: local dtype detect, then stages its own swizzled W tile into
// LDS straight from w1 (coalesced 16B reads of the L2-resident 64KB weights;
// bank-rotated ds_write_b16 scatter).  LDS halfword layout (same as old img):
//   sH[n*128 + ((k>>3)^(n&15))*8 + (k&7)] = W[k][n]
// MFMA loop and LDS-staged coalesced store epilogue identical to r2
// (counter-verified: WRITE_SIZE exact, 0 bank conflicts).
// Block 0 additionally publishes params+flag for the edge dispatch.
// ---------------------------------------------------------------------------
__global__ __launch_bounds__(256) void proj_all_kernel(
    const void* __restrict__ Zg, const void* __restrict__ Zd,
    const void* __restrict__ w1_gd, const void* __restrict__ w1_gg,
    const void* __restrict__ b1_gd, const void* __restrict__ b1_gg,
    const void* __restrict__ w2_gd, const void* __restrict__ b2_gd,
    const void* __restrict__ w2_gg, const void* __restrict__ b2_gg,
    float* __restrict__ params, int* __restrict__ flagout,
    unsigned short* __restrict__ A_gd, unsigned short* __restrict__ B_gd,
    unsigned short* __restrict__ A_gg, unsigned short* __restrict__ B_gg,
    int NG, int ND, int gblk)
{
    __shared__ uint4 sW[2048];  // 32 KB: detect scratch / W tile / out staging
    int tid  = threadIdx.x;
    int lane = tid & 63;
    int wave = tid >> 6;
    int nl   = lane & 15;
    int quad = lane >> 4;

    int flag = local_detect_s((const unsigned short*)Zg, (int*)sW);

    int b  = blockIdx.x;
    int ph = (b >= gblk) + (b >= 2 * gblk) + (b >= 3 * gblk);  // 0..3
    bool gene = ph < 3;
    int blk = b - ph * gblk;
    int M = gene ? NG : ND;
    const void* Z = gene ? Zg : Zd;
    const void* w1src = (ph == 0 || ph == 3) ? w1_gd : w1_gg;
    int part = (ph == 2 || ph == 3) ? 1 : 0;   // bottom half of w1 for ph2/ph3
    unsigned short* Out = ph == 0 ? A_gd : ph == 1 ? A_gg : ph == 2 ? B_gg : B_gd;
    const void* b1 = ph == 0 ? b1_gd : ph == 1 ? b1_gg : nullptr;

    // publish params + flag for the edge dispatch (cross-dispatch dependency)
    if (b == 0) {
        if (tid < 128) {
            params[tid]       = ldv(b1_gd, tid, flag);
            params[256 + tid] = ldv(b1_gg, tid, flag);
        } else {
            params[tid]       = ldv(w2_gd, tid - 128, flag);
            params[256 + tid] = ldv(w2_gg, tid - 128, flag);
        }
        if (tid == 0) {
            params[512] = ldv(b2_gd, 0, flag);
            params[513] = ldv(b2_gg, 0, flag);
            *flagout = flag;
        }
    }

    // ---- self-stage swizzled W tile into LDS ------------------------------
    {
        unsigned short* sH = (unsigned short*)sW;
        int n0 = (tid & 15) * 8;   // 8 consecutive n per thread
        int kb = tid >> 4;         // 16 k-values per pass
#pragma unroll
        for (int pass = 0; pass < 8; ++pass) {
            int k = pass * 16 + kb;
            unsigned short hw[8];
            if (flag) {
                uint4 v = *(const uint4*)((const unsigned short*)w1src +
                                          (size_t)(part * 128 + k) * 128 + n0);
                const unsigned short* pv = (const unsigned short*)&v;
#pragma unroll
                for (int j = 0; j < 8; ++j) hw[j] = pv[j];
            } else {
                const float* pf = (const float*)w1src + (size_t)(part * 128 + k) * 128 + n0;
                float4 f0 = *(const float4*)(pf);
                float4 f1 = *(const float4*)(pf + 4);
                hw[0] = f2b(f0.x); hw[1] = f2b(f0.y); hw[2] = f2b(f0.z); hw[3] = f2b(f0.w);
                hw[4] = f2b(f1.x); hw[5] = f2b(f1.y); hw[6] = f2b(f1.z); hw[7] = f2b(f1.w);
            }
#pragma unroll
            for (int jj = 0; jj < 8; ++jj) {
                int j = (jj + (tid & 7)) & 7;   // rotate start -> spread banks
                int n = n0 + j;
                sH[n * 128 + (((k >> 3) ^ (n & 15)) << 3) + (k & 7)] = hw[j];
            }
        }
    }

    int row0 = blk * 128 + wave * 32 + nl;
    int row1 = row0 + 16;
    int r0c = row0 < M ? row0 : (M - 1);
    int r1c = row1 < M ? row1 : (M - 1);

    short8 zf[2][4];
    if (flag) {
        const uint4* z0 = (const uint4*)Z + (size_t)r0c * 16;
        const uint4* z1 = (const uint4*)Z + (size_t)r1c * 16;
#pragma unroll
        for (int kc = 0; kc < 4; ++kc) {
            zf[0][kc] = __builtin_bit_cast(short8, z0[kc * 4 + quad]);
            zf[1][kc] = __builtin_bit_cast(short8, z1[kc * 4 + quad]);
        }
    } else {
        const float4* z0 = (const float4*)Z + (size_t)r0c * 32;
        const float4* z1 = (const float4*)Z + (size_t)r1c * 32;
#pragma unroll
        for (int kc = 0; kc < 4; ++kc) {
            int o = kc * 8 + quad * 2;
            zf[0][kc] = pack8(z0[o], z0[o + 1]);
            zf[1][kc] = pack8(z1[o], z1[o + 1]);
        }
    }

    __syncthreads();   // W tile staged, everyone's z in regs

    floatx4 acc[2][8];
#pragma unroll
    for (int rt = 0; rt < 2; ++rt)
#pragma unroll
        for (int nt = 0; nt < 8; ++nt)
            acc[rt][nt] = (floatx4){0.f, 0.f, 0.f, 0.f};

#pragma unroll
    for (int kc = 0; kc < 4; ++kc) {
        int p = (kc * 4 + quad) ^ nl;   // undo XOR swizzle
#pragma unroll
        for (int nt = 0; nt < 8; ++nt) {
            short8 wf = __builtin_bit_cast(short8, sW[(nt * 16 + nl) * 16 + p]);
            acc[0][nt] = __builtin_amdgcn_mfma_f32_16x16x32_bf16(wf, zf[0][kc], acc[0][nt], 0, 0, 0);
            acc[1][nt] = __builtin_amdgcn_mfma_f32_16x16x32_bf16(wf, zf[1][kc], acc[1][nt], 0, 0, 0);
        }
    }

    // ---- epilogue: LDS-staged coalesced stores (verified r2) --------------
    char* sOb = (char*)sW;
    __syncthreads();   // all waves done reading W
#pragma unroll
    for (int rt = 0; rt < 2; ++rt) {
        int h = wave * 16 + nl;
#pragma unroll
        for (int nt = 0; nt < 8; ++nt) {
            float4 bv = {0.f, 0.f, 0.f, 0.f};
            if (b1) {
                bv.x = ldv(b1, nt * 16 + quad * 4 + 0, flag);
                bv.y = ldv(b1, nt * 16 + quad * 4 + 1, flag);
                bv.z = ldv(b1, nt * 16 + quad * 4 + 2, flag);
                bv.w = ldv(b1, nt * 16 + quad * 4 + 3, flag);
            }
            unsigned lo = ((unsigned)f2b(acc[rt][nt][0] + bv.x)) |
                          (((unsigned)f2b(acc[rt][nt][1] + bv.y)) << 16);
            unsigned hi = ((unsigned)f2b(acc[rt][nt][2] + bv.z)) |
                          (((unsigned)f2b(acc[rt][nt][3] + bv.w)) << 16);
            uint2 v; v.x = lo; v.y = hi;
            *(uint2*)(sOb + h * 264 + nt * 32 + quad * 8) = v;
        }
        __syncthreads();
#pragma unroll
        for (int j = 0; j < 4; ++j) {
            int r = blk * 128 + rt * 16 + j * 32 + (tid >> 4);
            uint4 v = *(const uint4*)(sOb + (j * 16 + (tid >> 4)) * 264 + (tid & 15) * 16);
            if (r < M)
                *(uint4*)(Out + (size_t)r * HDIM + (tid & 15) * 8) = v;
        }
        if (rt == 0) __syncthreads();
    }
}

// ---------------------------------------------------------------------------
// edge: 8 lanes/edge, 2 edges per lane-group (r0 config: best measured).
// out[e] = relu(A[src]+B[dst]).w2 + b2  (b1 pre-folded into A).
// Byte-identical to the verified r2 version.
// ---------------------------------------------------------------------------
__global__ __launch_bounds__(256) void edge_kernel(
    const int* __restrict__ edges_gd, const int* __restrict__ edges_gg,
    const unsigned short* __restrict__ A_gd, const unsigned short* __restrict__ B_gd,
    const unsigned short* __restrict__ A_gg, const unsigned short* __restrict__ B_gg,
    const float* __restrict__ params,
    void* __restrict__ out, int E, int nb, const int* __restrict__ flagp)
{
    int rel = ((int)blockIdx.x >= nb) ? 1 : 0;
    int blk = blockIdx.x - rel * nb;
    const int* edges = rel ? edges_gg : edges_gd;
    const unsigned short* A = rel ? A_gg : A_gd;
    const unsigned short* B = rel ? B_gg : B_gd;
    const float* w2 = params + 128 + rel * 256;   // block-uniform
    float b2 = params[512 + rel];

    int tid  = threadIdx.x;
    int lane = tid & 63;
    int wave = tid >> 6;
    int nl   = lane & 7;    // lane within edge-group
    int grp  = lane >> 3;   // 8 groups per wave

    float w2f[16];
#pragma unroll
    for (int i = 0; i < 4; ++i) {
        float4 t = *(const float4*)(w2 + nl * 16 + i * 4);
        w2f[i * 4 + 0] = t.x; w2f[i * 4 + 1] = t.y;
        w2f[i * 4 + 2] = t.z; w2f[i * 4 + 3] = t.w;
    }

    int e0 = blk * 64 + (wave * 8 + grp) * 2;
    int e1 = e0 + 1;
    int emax = E - 2 > 0 ? E - 2 : 0;
    int ec = e0 < emax ? e0 : emax;     // clamped pair base (in-bounds int2)
    int sel = e0 - ec;                  // 0 normally; 1 only on odd tail
    int2 sp = *(const int2*)(edges + ec);
    int2 dp = *(const int2*)(edges + E + ec);
    int src0 = sel ? sp.y : sp.x;
    int dst0 = sel ? dp.y : dp.x;
    int src1 = sp.y;
    int dst1 = dp.y;

    const uint4* a0p = (const uint4*)(A + (size_t)src0 * HDIM) + nl * 2;
    const uint4* b0p = (const uint4*)(B + (size_t)dst0 * HDIM) + nl * 2;
    const uint4* a1p = (const uint4*)(A + (size_t)src1 * HDIM) + nl * 2;
    const uint4* b1p = (const uint4*)(B + (size_t)dst1 * HDIM) + nl * 2;
    uint4 a0[2] = {a0p[0], a0p[1]};
    uint4 c0[2] = {b0p[0], b0p[1]};
    uint4 a1[2] = {a1p[0], a1p[1]};
    uint4 c1[2] = {b1p[0], b1p[1]};

    float acc0 = 0.f, acc1 = 0.f;
#pragma unroll
    for (int i = 0; i < 2; ++i) {
        const unsigned* au0 = (const unsigned*)&a0[i];
        const unsigned* cu0 = (const unsigned*)&c0[i];
        const unsigned* au1 = (const unsigned*)&a1[i];
        const unsigned* cu1 = (const unsigned*)&c1[i];
#pragma unroll
        for (int j = 0; j < 4; ++j) {
            int ch = i * 8 + j * 2;
            float x0 = __uint_as_float(au0[j] << 16);
            float x1 = __uint_as_float(au0[j] & 0xffff0000u);
            float y0 = __uint_as_float(cu0[j] << 16);
            float y1 = __uint_as_float(cu0[j] & 0xffff0000u);
            acc0 = fmaf(fmaxf(x0 + y0, 0.f), w2f[ch], acc0);
            acc0 = fmaf(fmaxf(x1 + y1, 0.f), w2f[ch + 1], acc0);
            float u0 = __uint_as_float(au1[j] << 16);
            float u1 = __uint_as_float(au1[j] & 0xffff0000u);
            float v0 = __uint_as_float(cu1[j] << 16);
            float v1 = __uint_as_float(cu1[j] & 0xffff0000u);
            acc1 = fmaf(fmaxf(u0 + v0, 0.f), w2f[ch], acc1);
            acc1 = fmaf(fmaxf(u1 + v1, 0.f), w2f[ch + 1], acc1);
        }
    }
    acc0 += __shfl_xor(acc0, 1); acc1 += __shfl_xor(acc1, 1);
    acc0 += __shfl_xor(acc0, 2); acc1 += __shfl_xor(acc1, 2);
    acc0 += __shfl_xor(acc0, 4); acc1 += __shfl_xor(acc1, 4);

    if (nl == 0) {
        int flag = *flagp;
        size_t base = (size_t)rel * E;
        if (e0 < E) {
            float r = acc0 + b2;
            if (flag) ((unsigned short*)out)[base + e0] = f2b(r);
            else      ((float*)out)[base + e0] = r;
        }
        if (e1 < E) {
            float r = acc1 + b2;
            if (flag) ((unsigned short*)out)[base + e1] = f2b(r);
            else      ((float*)out)[base + e1] = r;
        }
    }
}

// ---------------------------------------------------------------------------
// Fallback path (ws too small): detect + full per-edge MLP, one edge/block.
// ---------------------------------------------------------------------------
__device__ __forceinline__ int local_detect(const unsigned short* zbits) {
    __shared__ int red[256];
    return local_detect_s(zbits, red);
}

__global__ __launch_bounds__(256) void detect_kernel(
    const unsigned short* __restrict__ zbits, int* __restrict__ flag)
{
    int f = local_detect(zbits);
    if (threadIdx.x == 0) *flag = f;
}

__global__ __launch_bounds__(128) void naive_edge_kernel(
    const int* __restrict__ edges,
    const void* __restrict__ zsrc, const void* __restrict__ zdst,
    const void* __restrict__ w1, const void* __restrict__ b1,
    const void* __restrict__ w2, const void* __restrict__ b2,
    void* __restrict__ out, size_t eoff, int E,
    const int* __restrict__ flagp)
{
    int flag = flagp ? *flagp : 0;
    __shared__ float zs[128], zd[128], red[128];
    int e = blockIdx.x;
    int n = threadIdx.x;
    int src = edges[e], dst = edges[E + e];
    zs[n] = ldv(zsrc, (size_t)src * HDIM + n, flag);
    zd[n] = ldv(zdst, (size_t)dst * HDIM + n, flag);
    __syncthreads();
    float acc = ldv(b1, n, flag);
    for (int k = 0; k < 128; ++k) acc = fmaf(zs[k], ldv(w1, (size_t)k * HDIM + n, flag), acc);
    for (int k = 0; k < 128; ++k) acc = fmaf(zd[k], ldv(w1, (size_t)(128 + k) * HDIM + n, flag), acc);
    red[n] = fmaxf(acc, 0.f) * ldv(w2, n, flag);
    __syncthreads();
    for (int s = 64; s > 0; s >>= 1) {
        if (n < s) red[n] += red[n + s];
        __syncthreads();
    }
    if (n == 0) {
        float r = red[0] + ldv(b2, 0, flag);
        if (flag) ((unsigned short*)out)[eoff + e] = f2b(r);
        else      ((float*)out)[eoff + e] = r;
    }
}

extern "C" void kernel_launch(void* const* d_in, const int* in_sizes, int n_in,
                              void* d_out, int out_size, void* d_ws, size_t ws_size,
                              hipStream_t stream)
{
    const void* z_gene = d_in[0];
    const void* z_dis  = d_in[1];
    const int* edges_gd = (const int*)d_in[2];
    const int* edges_gg = (const int*)d_in[3];
    const void* w1_gd = d_in[4];
    const void* b1_gd = d_in[5];
    const void* w2_gd = d_in[6];
    const void* b2_gd = d_in[7];
    const void* w1_gg = d_in[8];
    const void* b1_gg = d_in[9];
    const void* w2_gg = d_in[10];
    const void* b2_gg = d_in[11];

    int NG = in_sizes[0] / HDIM;   // 100000
    int ND = in_sizes[1] / HDIM;   // 20000
    int E  = in_sizes[2] / 2;      // 500000

    // workspace layout (bytes)
    size_t off_flag   = 0;
    size_t off_params = 256;
    size_t off_img    = 2560;          // unused now (kept for layout stability)
    size_t off_Agd    = off_img + 131072;
    size_t off_Bgd    = off_Agd + (size_t)NG * HDIM * 2;
    size_t off_Agg    = off_Bgd + (size_t)ND * HDIM * 2;
    size_t off_Bgg    = off_Agg + (size_t)NG * HDIM * 2;
    size_t need       = off_Bgg + (size_t)NG * HDIM * 2;

    char* ws = (char*)d_ws;

    if (ws_size < need) {
        const int* flagp = nullptr;
        if (ws_size >= 16) {
            detect_kernel<<<1, 256, 0, stream>>>((const unsigned short*)z_gene, (int*)ws);
            flagp = (const int*)ws;
        }
        naive_edge_kernel<<<E, 128, 0, stream>>>(edges_gd, z_gene, z_dis,
                                                 w1_gd, b1_gd, w2_gd, b2_gd,
                                                 d_out, 0, E, flagp);
        naive_edge_kernel<<<E, 128, 0, stream>>>(edges_gg, z_gene, z_gene,
                                                 w1_gg, b1_gg, w2_gg, b2_gg,
                                                 d_out, (size_t)E, E, flagp);
        return;
    }

    int* flag = (int*)(ws + off_flag);
    float* params = (float*)(ws + off_params);
    unsigned short* Agd = (unsigned short*)(ws + off_Agd);
    unsigned short* Bgd = (unsigned short*)(ws + off_Bgd);
    unsigned short* Agg = (unsigned short*)(ws + off_Agg);
    unsigned short* Bgg = (unsigned short*)(ws + off_Bgg);

    int gblk = (NG + 127) / 128;
    int dblk = (ND + 127) / 128;

    proj_all_kernel<<<3 * gblk + dblk, 256, 0, stream>>>(
        z_gene, z_dis,
        w1_gd, w1_gg, b1_gd, b1_gg,
        w2_gd, b2_gd, w2_gg, b2_gg,
        params, flag,
        Agd, Bgd, Agg, Bgg,
        NG, ND, gblk);

    int nb = (E + 63) / 64;
    edge_kernel<<<2 * nb, 256, 0, stream>>>(edges_gd, edges_gg, Agd, Bgd, Agg, Bgg,
                                            params, d_out, E, nb, flag);
}